// Round 3
// baseline (577.939 us; speedup 1.0000x reference)
//
#include <hip/hip_runtime.h>
#include <math.h>

#define B_  2
#define L_  2048
#define D_  1024
#define H_  16
#define HD_ 64
#define DF_ 4096
#define NR_ 4096   // B_*L_

typedef __bf16 bf16_t;
typedef bf16_t bf16x8 __attribute__((ext_vector_type(8)));
typedef float  f32x4  __attribute__((ext_vector_type(4)));
typedef unsigned short u16;
typedef u16 u16x8 __attribute__((ext_vector_type(8)));
typedef u16 u16x4 __attribute__((ext_vector_type(4)));
typedef unsigned int u32;
typedef u32 u32x2 __attribute__((ext_vector_type(2)));

__device__ __forceinline__ u16 f2bf(float f) {
  unsigned u = __float_as_uint(f);
  u += 0x7fffu + ((u >> 16) & 1u);   // round-nearest-even
  return (u16)(u >> 16);
}
__device__ __forceinline__ float bf2f(u16 s) {
  return __uint_as_float(((unsigned)s) << 16);
}
__device__ __forceinline__ float gelu_f(float h) {
  return h * 0.5f * (1.f + tanhf(0.79788456f * h * (1.f + 0.044715f * h * h)));
}

// async global->LDS, 16B per lane. LDS dest must be wave-uniform-base + lane*16.
__device__ __forceinline__ void async_copy16(void* lds, const void* g) {
  __builtin_amdgcn_global_load_lds(
      (const __attribute__((address_space(1))) unsigned int*)g,
      (__attribute__((address_space(3))) unsigned int*)lds, 16, 0, 0);
}

// ---------------------------------------------------------------- transpose+bf16
// out[n][k] = bf16(W[k][n]);  W is [K][N] fp32 row-major, out is [N][K] bf16.
__global__ __launch_bounds__(256) void transpose_conv(
    const float* __restrict__ W, u16* __restrict__ out, int K, int N) {
  __shared__ float T[64][65];
  const int tid = threadIdx.x;
  const int n0 = blockIdx.x * 64, k0 = blockIdx.y * 64;
  const int r = tid >> 2, c4 = (tid & 3) * 16;
  const float* src = W + (size_t)(k0 + r) * N + n0 + c4;
#pragma unroll
  for (int i = 0; i < 16; i += 4) {
    float4 f = *(const float4*)(src + i);
    T[r][c4 + i + 0] = f.x; T[r][c4 + i + 1] = f.y;
    T[r][c4 + i + 2] = f.z; T[r][c4 + i + 3] = f.w;
  }
  __syncthreads();
  u16* dst = out + (size_t)(n0 + r) * K + k0 + c4;
#pragma unroll
  for (int half = 0; half < 2; ++half) {
    u16x8 o8;
#pragma unroll
    for (int i = 0; i < 8; ++i) o8[i] = f2bf(T[c4 + half * 8 + i][r]);
    *(u16x8*)(dst + half * 8) = o8;
  }
}

__global__ __launch_bounds__(256) void concat_bias(
    const float* __restrict__ bq, const float* __restrict__ bk,
    const float* __restrict__ bv, float* __restrict__ bqkv) {
  int i = blockIdx.x * 256 + threadIdx.x;
  if (i < 3072) {
    float v = (i < 1024) ? bq[i] : (i < 2048) ? bk[i - 1024] : bv[i - 2048];
    bqkv[i] = v;
  }
}

__global__ __launch_bounds__(256) void rope_tables(
    float* __restrict__ cosT, float* __restrict__ sinT) {
  int i = blockIdx.x * 256 + threadIdx.x;   // L_*32 total
  int pos = i >> 5, d = i & 31;
  float invf = powf(10000.f, -(float)d / 32.f);
  float a = (float)pos * invf;
  cosT[i] = cosf(a);
  sinT[i] = sinf(a);
}

// in-place RoPE on q,k halves of qkv[NR_][3072].
// q additionally scaled by log2(e)/8 (exp2-domain softmax + 1/sqrt(HD)).
__global__ __launch_bounds__(256) void rope_apply(
    u16* __restrict__ qkv, const float* __restrict__ cosT,
    const float* __restrict__ sinT) {
  int i = blockIdx.x * 256 + threadIdx.x;  // NR_*2*16*4 = 524288 threads
  int d0 = (i & 3) * 8;
  int hh = (i >> 2) & 15;
  int qk = (i >> 6) & 1;
  int row = i >> 7;
  int pos = row & (L_ - 1);
  size_t base = (size_t)row * 3072 + qk * 1024 + hh * 64 + d0;
  u16x8 a = *(const u16x8*)(qkv + base);
  u16x8 bb = *(const u16x8*)(qkv + base + 32);
  float4 c0 = *(const float4*)(cosT + pos * 32 + d0);
  float4 c1 = *(const float4*)(cosT + pos * 32 + d0 + 4);
  float4 s0 = *(const float4*)(sinT + pos * 32 + d0);
  float4 s1 = *(const float4*)(sinT + pos * 32 + d0 + 4);
  const float qs = qk ? 1.f : 0.18033688f;   // log2e/8 folded into Q
  u16x8 ra, rb;
#pragma unroll
  for (int j = 0; j < 8; ++j) {
    float co = (j < 4) ? ((const float*)&c0)[j] : ((const float*)&c1)[j - 4];
    float si = (j < 4) ? ((const float*)&s0)[j] : ((const float*)&s1)[j - 4];
    float v0 = bf2f(a[j]), v1 = bf2f(bb[j]);
    ra[j] = f2bf((v0 * co - v1 * si) * qs);
    rb[j] = f2bf((v1 * co + v0 * si) * qs);
  }
  *(u16x8*)(qkv + base) = ra;
  *(u16x8*)(qkv + base + 32) = rb;
}

// ---------------------------------------------------------------- V transpose
// vt[bh][d][seq] <- qkv V-part.
__global__ __launch_bounds__(256) void v_transpose(
    const u16* __restrict__ qkv, u16* __restrict__ vt) {
  const int tid = threadIdx.x;
  const int d = tid & 63, sub = tid >> 6;
  const int s0 = (blockIdx.x * 4 + sub) * 8;
  const int bh = blockIdx.y, b = bh >> 4, h = bh & 15;
  u16x8 o;
#pragma unroll
  for (int i = 0; i < 8; ++i)
    o[i] = qkv[(size_t)(b * L_ + s0 + i) * 3072 + 2048 + h * 64 + d];
  *(u16x8*)(vt + ((size_t)bh * 64 + d) * 2048 + s0) = o;
}

// ---------------------------------------------------------------- LayerNorm
__global__ __launch_bounds__(256) void ln_kernel(
    const float* __restrict__ x, const float* __restrict__ gm,
    const float* __restrict__ bt, u16* __restrict__ out) {
  const int row = blockIdx.x, tid = threadIdx.x;
  const float4 v = ((const float4*)(x + (size_t)row * D_))[tid];
  float s = v.x + v.y + v.z + v.w;
#pragma unroll
  for (int m = 1; m < 64; m <<= 1) s += __shfl_xor(s, m);
  __shared__ float red[4], red2[4];
  if ((tid & 63) == 0) red[tid >> 6] = s;
  __syncthreads();
  const float mean = (red[0] + red[1] + red[2] + red[3]) * (1.f / D_);
  float d0 = v.x - mean, d1 = v.y - mean, d2 = v.z - mean, d3 = v.w - mean;
  float sq = d0 * d0 + d1 * d1 + d2 * d2 + d3 * d3;
#pragma unroll
  for (int m = 1; m < 64; m <<= 1) sq += __shfl_xor(sq, m);
  if ((tid & 63) == 0) red2[tid >> 6] = sq;
  __syncthreads();
  const float var = (red2[0] + red2[1] + red2[2] + red2[3]) * (1.f / D_);
  const float rstd = rsqrtf(var + 1e-5f);
  const int c = tid * 4;
  u16x4 o;
  o[0] = f2bf(d0 * rstd * gm[c + 0] + bt[c + 0]);
  o[1] = f2bf(d1 * rstd * gm[c + 1] + bt[c + 1]);
  o[2] = f2bf(d2 * rstd * gm[c + 2] + bt[c + 2]);
  o[3] = f2bf(d3 * rstd * gm[c + 3] + bt[c + 3]);
  ((u16x4*)(out + (size_t)row * D_))[tid] = o;
}

// out[row][c] = resid[row][c] + bias[c]   (f32, N=1024)
__global__ __launch_bounds__(256) void bias_resid_init(
    const float* __restrict__ resid, const float* __restrict__ bias,
    float* __restrict__ out) {
  int i = blockIdx.x * 256 + threadIdx.x;   // NR_*256 threads (float4 each)
  int c4 = (i & 255) * 4;
  float4 r = ((const float4*)resid)[i];
  float4 bv = *(const float4*)(bias + c4);
  r.x += bv.x; r.y += bv.y; r.z += bv.z; r.w += bv.w;
  ((float4*)out)[i] = r;
}

// ---------------------------------------------------------------- GEMM (m97-style)
// C[M,N] = A[M,K] * Bt[N,K]^T ; EPI: 0=+bias->bf16, 1=+bias,gelu->bf16,
// 3=split-K atomicAdd f32 (bias/resid pre-applied by bias_resid_init).
template <int EPI>
__global__ __launch_bounds__(256) void gemm_bt(
    const u16* __restrict__ A, const u16* __restrict__ Bt,
    const float* __restrict__ bias, void* __restrict__ out,
    int M, int N, int K) {
  __shared__ u16 As[128 * 32];
  __shared__ u16 Bs[128 * 32];
  const int tid = threadIdx.x;
  const int l = tid & 63, wid = tid >> 6;
  const int m0 = blockIdx.y * 128, n0 = blockIdx.x * 128;
  const int wr = wid >> 1, wc = wid & 1;
  const int ksub = K / gridDim.z;
  const int k0 = blockIdx.z * ksub;

  f32x4 acc[4][4];
#pragma unroll
  for (int mi = 0; mi < 4; ++mi)
#pragma unroll
    for (int ni = 0; ni < 4; ++ni) acc[mi][ni] = (f32x4){0.f, 0.f, 0.f, 0.f};

  for (int kb = k0; kb < k0 + ksub; kb += 32) {
#pragma unroll
    for (int r = 0; r < 2; ++r) {
      const int fo = r * 4096 + tid * 16;        // LDS byte offset
      const int row = fo >> 6, cb = fo & 63;     // tile row, col-bytes
      async_copy16((char*)As + fo, A + (size_t)(m0 + row) * K + kb + (cb >> 1));
      async_copy16((char*)Bs + fo, Bt + (size_t)(n0 + row) * K + kb + (cb >> 1));
    }
    __syncthreads();
    bf16x8 ag[4], bg[4];
#pragma unroll
    for (int mi = 0; mi < 4; ++mi) {
      int row = wr * 64 + mi * 16 + (l & 15);
      ag[mi] = *(const bf16x8*)((const char*)As + row * 64 + ((l >> 4) * 16));
    }
#pragma unroll
    for (int ni = 0; ni < 4; ++ni) {
      int row = wc * 64 + ni * 16 + (l & 15);
      bg[ni] = *(const bf16x8*)((const char*)Bs + row * 64 + ((l >> 4) * 16));
    }
#pragma unroll
    for (int mi = 0; mi < 4; ++mi)
#pragma unroll
      for (int ni = 0; ni < 4; ++ni)
        acc[mi][ni] = __builtin_amdgcn_mfma_f32_16x16x32_bf16(
            ag[mi], bg[ni], acc[mi][ni], 0, 0, 0);
    __syncthreads();
  }

  const int cl = l & 15, rq = l >> 4;
#pragma unroll
  for (int ni = 0; ni < 4; ++ni) {
    const int col = n0 + wc * 64 + ni * 16 + cl;
    const float bv = (EPI == 3) ? 0.f : bias[col];
#pragma unroll
    for (int mi = 0; mi < 4; ++mi) {
#pragma unroll
      for (int j = 0; j < 4; ++j) {
        const int rowg = m0 + wr * 64 + mi * 16 + rq * 4 + j;
        float v = acc[mi][ni][j] + bv;
        if (EPI == 0) {
          ((u16*)out)[(size_t)rowg * N + col] = f2bf(v);
        } else if (EPI == 1) {
          ((u16*)out)[(size_t)rowg * N + col] = f2bf(gelu_f(v));
        } else {
          atomicAdd(&((float*)out)[(size_t)rowg * N + col], v);
        }
      }
    }
  }
}

// ---------------------------------------------------------------- flash attention
// Swapped-operand: S^T = mfma(K,Q) so each lane owns one q-row (in-reg softmax,
// only 4 shuffles/tile); O^T = mfma(V^T,P) so rescale needs no shuffles.
// Barrier-free; P through per-wave swizzled LDS. exp2 domain (Q pre-scaled).
__global__ __launch_bounds__(256, 4) void attn_kernel(
    const u16* __restrict__ qkv, const u16* __restrict__ vt,
    u16* __restrict__ o) {
  const int tid = threadIdx.x, l = tid & 63, wid = tid >> 6;
  // XCD-aware decomposition: heavy q-blocks first.
  const int id = blockIdx.x;
  const int seq = id >> 3, xcd = id & 7;
  const int bh = xcd * 4 + (seq & 3);
  const int qblk = 31 - (seq >> 2);
  const int b = bh >> 4, h = bh & 15;
  const int q0 = qblk * 64;
  __shared__ u16 Ps[4][16 * 64];   // per-wave private P[qrow][kcol], swizzled

  const int r16 = l & 15, g = l >> 4;

  // Q B-fragments: B[col=qrow=r16][k=d-slice]
  const int qrow_g = b * L_ + q0 + wid * 16 + r16;
  const u16* qp = qkv + (size_t)qrow_g * 3072 + h * 64 + g * 8;
  const bf16x8 qb0 = *(const bf16x8*)qp;
  const bf16x8 qb1 = *(const bf16x8*)(qp + 32);

  const u16* kbase = qkv + (size_t)(b * L_ + r16) * 3072 + 1024 + h * 64 + g * 8;
  const u16* vbase = vt + ((size_t)bh * 64 + r16) * 2048 + g * 8;

  float m_ = -1e30f, ls = 0.f;
  f32x4 oa[4];
#pragma unroll
  for (int t = 0; t < 4; ++t) oa[t] = (f32x4){0.f, 0.f, 0.f, 0.f};

  char* const psw = (char*)&Ps[wid][0] + r16 * 128;
  const int pswz = (r16 & 7) << 4;

  for (int kb = 0; kb <= q0; kb += 64) {
    const bool diag = (kb == q0);

    // ---- S^T = K Q^T : lane holds p[t][j] = S[kcol = t*16+g*4+j][qrow = r16]
    float p[4][4];
#pragma unroll
    for (int t = 0; t < 4; ++t) {
      if (diag && t > wid) {     // fully-masked sub-tile: skip MFMA
#pragma unroll
        for (int j = 0; j < 4; ++j) p[t][j] = -1e30f;
        continue;
      }
      const u16* kp = kbase + (size_t)(kb + t * 16) * 3072;
      f32x4 s = (f32x4){0.f, 0.f, 0.f, 0.f};
      s = __builtin_amdgcn_mfma_f32_16x16x32_bf16(*(const bf16x8*)kp, qb0, s, 0, 0, 0);
      s = __builtin_amdgcn_mfma_f32_16x16x32_bf16(*(const bf16x8*)(kp + 32), qb1, s, 0, 0, 0);
      if (diag && t == wid) {
#pragma unroll
        for (int j = 0; j < 4; ++j)
          p[t][j] = (g * 4 + j <= r16) ? s[j] : -1e30f;
      } else {
#pragma unroll
        for (int j = 0; j < 4; ++j) p[t][j] = s[j];
      }
    }

    // ---- V fragments issued early (independent of softmax)
    bf16x8 vf[4][2];
#pragma unroll
    for (int t = 0; t < 4; ++t) {
      const u16* vp = vbase + (size_t)t * 16 * 2048 + kb;
      vf[t][0] = *(const bf16x8*)vp;
      vf[t][1] = *(const bf16x8*)(vp + 32);
    }

    // ---- online softmax: per-lane row, only 4 cross-lane shuffles
    float pm = -1e30f;
#pragma unroll
    for (int t = 0; t < 4; ++t)
#pragma unroll
      for (int j = 0; j < 4; ++j) pm = fmaxf(pm, p[t][j]);
    pm = fmaxf(pm, __shfl_xor(pm, 16));
    pm = fmaxf(pm, __shfl_xor(pm, 32));
    const float mn = fmaxf(m_, pm);
    const float sc = exp2f(m_ - mn);
    float rs = 0.f;
#pragma unroll
    for (int t = 0; t < 4; ++t)
#pragma unroll
      for (int j = 0; j < 4; ++j) { p[t][j] = exp2f(p[t][j] - mn); rs += p[t][j]; }
    rs += __shfl_xor(rs, 16);
    rs += __shfl_xor(rs, 32);
    ls = ls * sc + rs;
    m_ = mn;
#pragma unroll
    for (int t = 0; t < 4; ++t) oa[t] *= sc;

    // ---- P -> per-wave LDS (bf16, 4x b64 writes, swizzled)
#pragma unroll
    for (int t = 0; t < 4; ++t) {
      u32x2 w;
      w[0] = (u32)f2bf(p[t][0]) | ((u32)f2bf(p[t][1]) << 16);
      w[1] = (u32)f2bf(p[t][2]) | ((u32)f2bf(p[t][3]) << 16);
      *(u32x2*)(psw + ((t * 32 + g * 8) ^ pswz)) = w;
    }

    // ---- O^T += V^T P : oa[t][j] = O[d = t*16+g*4+j][qrow = r16]
#pragma unroll
    for (int kc = 0; kc < 2; ++kc) {
      bf16x8 pf = *(const bf16x8*)(psw + ((kc * 64 + g * 16) ^ pswz));
#pragma unroll
      for (int t = 0; t < 4; ++t)
        oa[t] = __builtin_amdgcn_mfma_f32_16x16x32_bf16(vf[t][kc], pf, oa[t], 0, 0, 0);
    }
  }

  // ---- normalize + store (per-lane 1/ls, no shuffles)
  const float inv = 1.f / ls;
  u16* op = o + (size_t)qrow_g * D_ + h * 64;
#pragma unroll
  for (int t = 0; t < 4; ++t)
#pragma unroll
    for (int j = 0; j < 4; ++j)
      op[t * 16 + g * 4 + j] = f2bf(oa[t][j] * inv);
}

// ---------------------------------------------------------------- launch
extern "C" void kernel_launch(void* const* d_in, const int* in_sizes, int n_in,
                              void* d_out, int out_size, void* d_ws, size_t ws_size,
                              hipStream_t stream) {
  (void)in_sizes; (void)n_in; (void)out_size; (void)ws_size;
  const float* x    = (const float*)d_in[0];
  const float* Wq   = (const float*)d_in[2];
  const float* bq   = (const float*)d_in[3];
  const float* Wk   = (const float*)d_in[4];
  const float* bk   = (const float*)d_in[5];
  const float* Wv   = (const float*)d_in[6];
  const float* bv   = (const float*)d_in[7];
  const float* Wo   = (const float*)d_in[8];
  const float* bo   = (const float*)d_in[9];
  const float* ln1g = (const float*)d_in[10];
  const float* ln1b = (const float*)d_in[11];
  const float* W1   = (const float*)d_in[12];
  const float* b1   = (const float*)d_in[13];
  const float* W2   = (const float*)d_in[14];
  const float* b2   = (const float*)d_in[15];
  const float* ln2g = (const float*)d_in[16];
  const float* ln2b = (const float*)d_in[17];
  float* out = (float*)d_out;
  char* ws = (char*)d_ws;

  u16*   wqkvT = (u16*)(ws + 0);              // [3072][1024] bf16
  u16*   woT   = (u16*)(ws + 6291456);        // [1024][1024]
  u16*   w1T   = (u16*)(ws + 8388608);        // [4096][1024]
  u16*   w2T   = (u16*)(ws + 16777216);       // [1024][4096]
  float* bqkv  = (float*)(ws + 25165824);     // [3072]
  float* cosT  = (float*)(ws + 25178112);     // [2048][32]
  float* sinT  = (float*)(ws + 25440256);
  float* x2    = (float*)(ws + 25702400);     // [4096][1024] f32
  u16*   lnbuf = (u16*)(ws + 42479616);       // [4096][1024] bf16 (ln1/ln2)
  u16*   vtb   = lnbuf;                       // vt[32][64][2048] overlays lnbuf
  u16*   qkv   = (u16*)(ws + 50868224);       // [4096][3072] bf16
  u16*   attnO = (u16*)(ws + 76034048);       // [4096][1024] bf16
  u16*   hbuf  = qkv;                         // [4096][4096] bf16 overlays qkv+attnO

  const dim3 blk(256);
  // weights -> B^T bf16
  transpose_conv<<<dim3(16, 16), blk, 0, stream>>>(Wq, wqkvT, 1024, 1024);
  transpose_conv<<<dim3(16, 16), blk, 0, stream>>>(Wk, wqkvT + 1024 * 1024, 1024, 1024);
  transpose_conv<<<dim3(16, 16), blk, 0, stream>>>(Wv, wqkvT + 2048 * 1024, 1024, 1024);
  transpose_conv<<<dim3(16, 16), blk, 0, stream>>>(Wo, woT, 1024, 1024);
  transpose_conv<<<dim3(64, 16), blk, 0, stream>>>(W1, w1T, 1024, 4096);
  transpose_conv<<<dim3(16, 64), blk, 0, stream>>>(W2, w2T, 4096, 1024);
  concat_bias<<<12, blk, 0, stream>>>(bq, bk, bv, bqkv);
  rope_tables<<<256, blk, 0, stream>>>(cosT, sinT);

  // LN1 -> fused QKV GEMM -> RoPE -> V^T -> attention
  ln_kernel<<<NR_, blk, 0, stream>>>(x, ln1g, ln1b, lnbuf);
  gemm_bt<0><<<dim3(24, 32, 1), blk, 0, stream>>>(lnbuf, wqkvT, bqkv,
                                                  qkv, NR_, 3072, 1024);
  rope_apply<<<2048, blk, 0, stream>>>(qkv, cosT, sinT);
  v_transpose<<<dim3(64, 32), blk, 0, stream>>>(qkv, vtb);
  attn_kernel<<<1024, blk, 0, stream>>>(qkv, vtb, attnO);

  // O-proj (split-K=2, atomic) + residual -> LN2 -> MLP
  bias_resid_init<<<4096, blk, 0, stream>>>(x, bo, x2);
  gemm_bt<3><<<dim3(8, 32, 2), blk, 0, stream>>>(attnO, woT, nullptr,
                                                 x2, NR_, 1024, 1024);
  ln_kernel<<<NR_, blk, 0, stream>>>(x2, ln2g, ln2b, lnbuf);
  gemm_bt<1><<<dim3(32, 32, 1), blk, 0, stream>>>(lnbuf, w1T, b1,
                                                  hbuf, NR_, 4096, 1024);
  bias_resid_init<<<4096, blk, 0, stream>>>(x2, b2, out);
  gemm_bt<3><<<dim3(8, 32, 4), blk, 0, stream>>>(hbuf, w2T, nullptr,
                                                 out, NR_, 1024, 4096);
}

// Round 4
// 455.105 us; speedup vs baseline: 1.2699x; 1.2699x over previous
//
#include <hip/hip_runtime.h>
#include <math.h>

#define B_  2
#define L_  2048
#define D_  1024
#define H_  16
#define HD_ 64
#define DF_ 4096
#define NR_ 4096   // B_*L_

typedef __bf16 bf16_t;
typedef bf16_t bf16x8 __attribute__((ext_vector_type(8)));
typedef float  f32x4  __attribute__((ext_vector_type(4)));
typedef unsigned short u16;
typedef u16 u16x8 __attribute__((ext_vector_type(8)));
typedef u16 u16x4 __attribute__((ext_vector_type(4)));
typedef unsigned int u32;
typedef u32 u32x2 __attribute__((ext_vector_type(2)));

__device__ __forceinline__ u16 f2bf(float f) {
  unsigned u = __float_as_uint(f);
  u += 0x7fffu + ((u >> 16) & 1u);   // round-nearest-even
  return (u16)(u >> 16);
}
__device__ __forceinline__ float bf2f(u16 s) {
  return __uint_as_float(((unsigned)s) << 16);
}
__device__ __forceinline__ float gelu_f(float h) {
  return h * 0.5f * (1.f + tanhf(0.79788456f * h * (1.f + 0.044715f * h * h)));
}

// async global->LDS, 16B per lane. LDS dest must be wave-uniform-base + lane*16.
__device__ __forceinline__ void async_copy16(void* lds, const void* g) {
  __builtin_amdgcn_global_load_lds(
      (const __attribute__((address_space(1))) unsigned int*)g,
      (__attribute__((address_space(3))) unsigned int*)lds, 16, 0, 0);
}

// ---------------------------------------------------------------- transpose+bf16
// out[n][k] = bf16(W[k][n]);  W is [K][N] fp32 row-major, out is [N][K] bf16.
__global__ __launch_bounds__(256) void transpose_conv(
    const float* __restrict__ W, u16* __restrict__ out, int K, int N) {
  __shared__ float T[64][65];
  const int tid = threadIdx.x;
  const int n0 = blockIdx.x * 64, k0 = blockIdx.y * 64;
  const int r = tid >> 2, c4 = (tid & 3) * 16;
  const float* src = W + (size_t)(k0 + r) * N + n0 + c4;
#pragma unroll
  for (int i = 0; i < 16; i += 4) {
    float4 f = *(const float4*)(src + i);
    T[r][c4 + i + 0] = f.x; T[r][c4 + i + 1] = f.y;
    T[r][c4 + i + 2] = f.z; T[r][c4 + i + 3] = f.w;
  }
  __syncthreads();
  u16* dst = out + (size_t)(n0 + r) * K + k0 + c4;
#pragma unroll
  for (int half = 0; half < 2; ++half) {
    u16x8 o8;
#pragma unroll
    for (int i = 0; i < 8; ++i) o8[i] = f2bf(T[c4 + half * 8 + i][r]);
    *(u16x8*)(dst + half * 8) = o8;
  }
}

__global__ __launch_bounds__(256) void concat_bias(
    const float* __restrict__ bq, const float* __restrict__ bk,
    const float* __restrict__ bv, float* __restrict__ bqkv) {
  int i = blockIdx.x * 256 + threadIdx.x;
  if (i < 3072) {
    float v = (i < 1024) ? bq[i] : (i < 2048) ? bk[i - 1024] : bv[i - 2048];
    bqkv[i] = v;
  }
}

__global__ __launch_bounds__(256) void rope_tables(
    float* __restrict__ cosT, float* __restrict__ sinT) {
  int i = blockIdx.x * 256 + threadIdx.x;   // L_*32 total
  int pos = i >> 5, d = i & 31;
  float invf = powf(10000.f, -(float)d / 32.f);
  float a = (float)pos * invf;
  cosT[i] = cosf(a);
  sinT[i] = sinf(a);
}

// in-place RoPE on q,k halves of qkv[NR_][3072].
// q additionally scaled by log2(e)/8 (exp2-domain softmax + 1/sqrt(HD)).
__global__ __launch_bounds__(256) void rope_apply(
    u16* __restrict__ qkv, const float* __restrict__ cosT,
    const float* __restrict__ sinT) {
  int i = blockIdx.x * 256 + threadIdx.x;  // NR_*2*16*4 = 524288 threads
  int d0 = (i & 3) * 8;
  int hh = (i >> 2) & 15;
  int qk = (i >> 6) & 1;
  int row = i >> 7;
  int pos = row & (L_ - 1);
  size_t base = (size_t)row * 3072 + qk * 1024 + hh * 64 + d0;
  u16x8 a = *(const u16x8*)(qkv + base);
  u16x8 bb = *(const u16x8*)(qkv + base + 32);
  float4 c0 = *(const float4*)(cosT + pos * 32 + d0);
  float4 c1 = *(const float4*)(cosT + pos * 32 + d0 + 4);
  float4 s0 = *(const float4*)(sinT + pos * 32 + d0);
  float4 s1 = *(const float4*)(sinT + pos * 32 + d0 + 4);
  const float qs = qk ? 1.f : 0.18033688f;   // log2e/8 folded into Q
  u16x8 ra, rb;
#pragma unroll
  for (int j = 0; j < 8; ++j) {
    float co = (j < 4) ? ((const float*)&c0)[j] : ((const float*)&c1)[j - 4];
    float si = (j < 4) ? ((const float*)&s0)[j] : ((const float*)&s1)[j - 4];
    float v0 = bf2f(a[j]), v1 = bf2f(bb[j]);
    ra[j] = f2bf((v0 * co - v1 * si) * qs);
    rb[j] = f2bf((v1 * co + v0 * si) * qs);
  }
  *(u16x8*)(qkv + base) = ra;
  *(u16x8*)(qkv + base + 32) = rb;
}

// ---------------------------------------------------------------- V transpose
// vt[bh][d][seq] <- qkv V-part.
__global__ __launch_bounds__(256) void v_transpose(
    const u16* __restrict__ qkv, u16* __restrict__ vt) {
  const int tid = threadIdx.x;
  const int d = tid & 63, sub = tid >> 6;
  const int s0 = (blockIdx.x * 4 + sub) * 8;
  const int bh = blockIdx.y, b = bh >> 4, h = bh & 15;
  u16x8 o;
#pragma unroll
  for (int i = 0; i < 8; ++i)
    o[i] = qkv[(size_t)(b * L_ + s0 + i) * 3072 + 2048 + h * 64 + d];
  *(u16x8*)(vt + ((size_t)bh * 64 + d) * 2048 + s0) = o;
}

// ---------------------------------------------------------------- LayerNorm
__global__ __launch_bounds__(256) void ln_kernel(
    const float* __restrict__ x, const float* __restrict__ gm,
    const float* __restrict__ bt, u16* __restrict__ out) {
  const int row = blockIdx.x, tid = threadIdx.x;
  const float4 v = ((const float4*)(x + (size_t)row * D_))[tid];
  float s = v.x + v.y + v.z + v.w;
#pragma unroll
  for (int m = 1; m < 64; m <<= 1) s += __shfl_xor(s, m);
  __shared__ float red[4], red2[4];
  if ((tid & 63) == 0) red[tid >> 6] = s;
  __syncthreads();
  const float mean = (red[0] + red[1] + red[2] + red[3]) * (1.f / D_);
  float d0 = v.x - mean, d1 = v.y - mean, d2 = v.z - mean, d3 = v.w - mean;
  float sq = d0 * d0 + d1 * d1 + d2 * d2 + d3 * d3;
#pragma unroll
  for (int m = 1; m < 64; m <<= 1) sq += __shfl_xor(sq, m);
  if ((tid & 63) == 0) red2[tid >> 6] = sq;
  __syncthreads();
  const float var = (red2[0] + red2[1] + red2[2] + red2[3]) * (1.f / D_);
  const float rstd = rsqrtf(var + 1e-5f);
  const int c = tid * 4;
  u16x4 o;
  o[0] = f2bf(d0 * rstd * gm[c + 0] + bt[c + 0]);
  o[1] = f2bf(d1 * rstd * gm[c + 1] + bt[c + 1]);
  o[2] = f2bf(d2 * rstd * gm[c + 2] + bt[c + 2]);
  o[3] = f2bf(d3 * rstd * gm[c + 3] + bt[c + 3]);
  ((u16x4*)(out + (size_t)row * D_))[tid] = o;
}

// ---------------------------------------------------------------- GEMM (m97-style)
// C[M,N] = A[M,K] * Bt[N,K]^T (+bias[n]) ; EPI: 0=bf16, 1=gelu->bf16, 2=+resid->f32
template <int EPI>
__global__ __launch_bounds__(256) void gemm_bt(
    const u16* __restrict__ A, const u16* __restrict__ Bt,
    const float* __restrict__ bias, const float* __restrict__ resid,
    void* __restrict__ out, int M, int N, int K) {
  __shared__ u16 As[128 * 32];
  __shared__ u16 Bs[128 * 32];
  const int tid = threadIdx.x;
  const int l = tid & 63, wid = tid >> 6;
  const int m0 = blockIdx.y * 128, n0 = blockIdx.x * 128;
  const int wr = wid >> 1, wc = wid & 1;

  f32x4 acc[4][4];
#pragma unroll
  for (int mi = 0; mi < 4; ++mi)
#pragma unroll
    for (int ni = 0; ni < 4; ++ni) acc[mi][ni] = (f32x4){0.f, 0.f, 0.f, 0.f};

  for (int kb = 0; kb < K; kb += 32) {
#pragma unroll
    for (int r = 0; r < 2; ++r) {
      const int fo = r * 4096 + tid * 16;        // LDS byte offset
      const int row = fo >> 6, cb = fo & 63;     // tile row, col-bytes
      async_copy16((char*)As + fo, A + (size_t)(m0 + row) * K + kb + (cb >> 1));
      async_copy16((char*)Bs + fo, Bt + (size_t)(n0 + row) * K + kb + (cb >> 1));
    }
    __syncthreads();
    bf16x8 ag[4], bg[4];
#pragma unroll
    for (int mi = 0; mi < 4; ++mi) {
      int row = wr * 64 + mi * 16 + (l & 15);
      ag[mi] = *(const bf16x8*)((const char*)As + row * 64 + ((l >> 4) * 16));
    }
#pragma unroll
    for (int ni = 0; ni < 4; ++ni) {
      int row = wc * 64 + ni * 16 + (l & 15);
      bg[ni] = *(const bf16x8*)((const char*)Bs + row * 64 + ((l >> 4) * 16));
    }
#pragma unroll
    for (int mi = 0; mi < 4; ++mi)
#pragma unroll
      for (int ni = 0; ni < 4; ++ni)
        acc[mi][ni] = __builtin_amdgcn_mfma_f32_16x16x32_bf16(
            ag[mi], bg[ni], acc[mi][ni], 0, 0, 0);
    __syncthreads();
  }

  const int cl = l & 15, rq = l >> 4;
#pragma unroll
  for (int ni = 0; ni < 4; ++ni) {
    const int col = n0 + wc * 64 + ni * 16 + cl;
    const float bv = bias[col];
#pragma unroll
    for (int mi = 0; mi < 4; ++mi) {
#pragma unroll
      for (int j = 0; j < 4; ++j) {
        const int rowg = m0 + wr * 64 + mi * 16 + rq * 4 + j;
        float v = acc[mi][ni][j] + bv;
        if (EPI == 0) {
          ((u16*)out)[(size_t)rowg * N + col] = f2bf(v);
        } else if (EPI == 1) {
          ((u16*)out)[(size_t)rowg * N + col] = f2bf(gelu_f(v));
        } else {
          ((float*)out)[(size_t)rowg * N + col] =
              v + resid[(size_t)rowg * N + col];
        }
      }
    }
  }
}

// ---------------------------------------------------------------- flash attention
// LDS-staged K/V shared by 4 waves, double-buffered via global_load_lds with
// counted vmcnt (never drained) + raw s_barrier. Swapped-operand in-register
// softmax (lane owns a q-row); per-wave P in LDS; exp2 domain.
// XOR-swizzled K/V LDS layout via pre-swizzled global source addresses.
__global__ __launch_bounds__(256, 4) void attn_kernel(
    const u16* __restrict__ qkv, const u16* __restrict__ vt,
    u16* __restrict__ o) {
  const int tid = threadIdx.x, l = tid & 63, wid = tid >> 6;
  // XCD-aware decomposition: heavy q-blocks first.
  const int id = blockIdx.x;
  const int seq = id >> 3, xcd = id & 7;
  const int bh = xcd * 4 + (seq & 3);
  const int qblk = 31 - (seq >> 2);
  const int b = bh >> 4, h = bh & 15;
  const int q0 = qblk * 64;

  __shared__ u16 Ks[2][64 * 64];   // [kvrow][d], 128B rows, XOR-swizzled
  __shared__ u16 Vs[2][64 * 64];   // [d][kvseq], 128B rows, XOR-swizzled
  __shared__ u16 Ps[4][16 * 64];   // per-wave P[qrow][kcol], swizzled

  const int r16 = l & 15, g = l >> 4;

  // staging geometry: chunk c = tid (+256), row = c>>3, colb = (c&7)*16.
  // source column pre-swizzled so LDS linear layout == swizzled layout.
  const int srow = tid >> 3, scb = (tid & 7) * 16;
  const int scol = (scb ^ ((srow & 7) << 4)) >> 1;   // element offset in row
  const u16* ksrc = qkv + (size_t)(b * L_ + srow) * 3072 + 1024 + h * 64 + scol;
  const u16* vsrc = vt + ((size_t)bh * 64 + srow) * 2048 + scol;

#define STAGE_KV(BUF, KB) do {                                              \
    async_copy16((char*)&Ks[BUF][0] + tid * 16,                             \
                 ksrc + (size_t)(KB) * 3072);                               \
    async_copy16((char*)&Ks[BUF][0] + tid * 16 + 4096,                      \
                 ksrc + (size_t)(KB) * 3072 + 32 * 3072);                   \
    async_copy16((char*)&Vs[BUF][0] + tid * 16, vsrc + (KB));               \
    async_copy16((char*)&Vs[BUF][0] + tid * 16 + 4096,                      \
                 vsrc + (KB) + 32 * 2048);                                  \
  } while (0)

  // Q B-fragments: B[col=qrow=r16][k=d-slice]; q pre-scaled (log2e/8) + roped.
  const int qrow_g = b * L_ + q0 + wid * 16 + r16;
  const u16* qp = qkv + (size_t)qrow_g * 3072 + h * 64 + g * 8;
  const bf16x8 qb0 = *(const bf16x8*)qp;
  const bf16x8 qb1 = *(const bf16x8*)(qp + 32);

  float m_ = -1e30f, ls = 0.f;
  f32x4 oa[4];
#pragma unroll
  for (int t = 0; t < 4; ++t) oa[t] = (f32x4){0.f, 0.f, 0.f, 0.f};

  char* const psw = (char*)&Ps[wid][0] + r16 * 128;
  const int pswz = (r16 & 7) << 4;

  const int nt = qblk + 1;
  int buf = 0;
  STAGE_KV(0, 0);

  for (int it = 0; it < nt; ++it) {
    const int kb = it * 64;
    const bool diag = (it == nt - 1);
    STAGE_KV(buf ^ 1, diag ? kb : kb + 64);      // uniform 4 loads (dummy on last)
    asm volatile("s_waitcnt vmcnt(4)" ::: "memory");  // cur staged; next in flight
    __builtin_amdgcn_s_barrier();

    const char* kb_l = (const char*)&Ks[0][0] + buf * 8192;
    const char* vb_l = (const char*)&Vs[0][0] + buf * 8192;

    // ---- S^T = K Q^T : lane holds p[t][j] = S[kcol=t*16+g*4+j][qrow=r16]
    float p[4][4];
#pragma unroll
    for (int t = 0; t < 4; ++t) {
      if (diag && t > wid) {     // fully-masked sub-tile: skip MFMA
#pragma unroll
        for (int j = 0; j < 4; ++j) p[t][j] = -1e30f;
        continue;
      }
      const int krow = t * 16 + r16, swzk = (krow & 7) << 4;
      bf16x8 k0 = *(const bf16x8*)(kb_l + krow * 128 + ((g * 16) ^ swzk));
      bf16x8 k1 = *(const bf16x8*)(kb_l + krow * 128 + ((64 + g * 16) ^ swzk));
      f32x4 s = (f32x4){0.f, 0.f, 0.f, 0.f};
      s = __builtin_amdgcn_mfma_f32_16x16x32_bf16(k0, qb0, s, 0, 0, 0);
      s = __builtin_amdgcn_mfma_f32_16x16x32_bf16(k1, qb1, s, 0, 0, 0);
      if (diag && t == wid) {
#pragma unroll
        for (int j = 0; j < 4; ++j)
          p[t][j] = (g * 4 + j <= r16) ? s[j] : -1e30f;
      } else {
#pragma unroll
        for (int j = 0; j < 4; ++j) p[t][j] = s[j];
      }
    }

    // ---- online softmax: per-lane row, 4 cross-lane shuffles total
    float pm = -1e30f;
#pragma unroll
    for (int t = 0; t < 4; ++t)
#pragma unroll
      for (int j = 0; j < 4; ++j) pm = fmaxf(pm, p[t][j]);
    pm = fmaxf(pm, __shfl_xor(pm, 16));
    pm = fmaxf(pm, __shfl_xor(pm, 32));
    const float mn = fmaxf(m_, pm);
    const float sc = exp2f(m_ - mn);
    float rs = 0.f;
#pragma unroll
    for (int t = 0; t < 4; ++t)
#pragma unroll
      for (int j = 0; j < 4; ++j) { p[t][j] = exp2f(p[t][j] - mn); rs += p[t][j]; }
    rs += __shfl_xor(rs, 16);
    rs += __shfl_xor(rs, 32);
    ls = ls * sc + rs;
    m_ = mn;
#pragma unroll
    for (int t = 0; t < 4; ++t) oa[t] *= sc;

    // ---- P -> per-wave LDS (bf16, 4x b64 writes, swizzled)
#pragma unroll
    for (int t = 0; t < 4; ++t) {
      u32x2 w;
      w[0] = (u32)f2bf(p[t][0]) | ((u32)f2bf(p[t][1]) << 16);
      w[1] = (u32)f2bf(p[t][2]) | ((u32)f2bf(p[t][3]) << 16);
      *(u32x2*)(psw + ((t * 32 + g * 8) ^ pswz)) = w;
    }

    // ---- O^T += V^T P : oa[t][j] = O[d=t*16+g*4+j][qrow=r16]
#pragma unroll
    for (int kc = 0; kc < 2; ++kc) {
      bf16x8 pf = *(const bf16x8*)(psw + ((kc * 64 + g * 16) ^ pswz));
#pragma unroll
      for (int t = 0; t < 4; ++t) {
        const int vrow = t * 16 + r16, swzv = (vrow & 7) << 4;
        bf16x8 vf = *(const bf16x8*)(vb_l + vrow * 128 +
                                     ((kc * 64 + g * 16) ^ swzv));
        oa[t] = __builtin_amdgcn_mfma_f32_16x16x32_bf16(vf, pf, oa[t], 0, 0, 0);
      }
    }

    __builtin_amdgcn_s_barrier();   // all waves done reading buf
    buf ^= 1;
  }
#undef STAGE_KV

  // ---- normalize + store (per-lane 1/ls, no shuffles)
  const float inv = 1.f / ls;
  u16* op = o + (size_t)qrow_g * D_ + h * 64;
#pragma unroll
  for (int t = 0; t < 4; ++t)
#pragma unroll
    for (int j = 0; j < 4; ++j)
      op[t * 16 + g * 4 + j] = f2bf(oa[t][j] * inv);
}

// ---------------------------------------------------------------- launch
extern "C" void kernel_launch(void* const* d_in, const int* in_sizes, int n_in,
                              void* d_out, int out_size, void* d_ws, size_t ws_size,
                              hipStream_t stream) {
  (void)in_sizes; (void)n_in; (void)out_size; (void)ws_size;
  const float* x    = (const float*)d_in[0];
  const float* Wq   = (const float*)d_in[2];
  const float* bq   = (const float*)d_in[3];
  const float* Wk   = (const float*)d_in[4];
  const float* bk   = (const float*)d_in[5];
  const float* Wv   = (const float*)d_in[6];
  const float* bv   = (const float*)d_in[7];
  const float* Wo   = (const float*)d_in[8];
  const float* bo   = (const float*)d_in[9];
  const float* ln1g = (const float*)d_in[10];
  const float* ln1b = (const float*)d_in[11];
  const float* W1   = (const float*)d_in[12];
  const float* b1   = (const float*)d_in[13];
  const float* W2   = (const float*)d_in[14];
  const float* b2   = (const float*)d_in[15];
  const float* ln2g = (const float*)d_in[16];
  const float* ln2b = (const float*)d_in[17];
  float* out = (float*)d_out;
  char* ws = (char*)d_ws;

  u16*   wqkvT = (u16*)(ws + 0);              // [3072][1024] bf16
  u16*   woT   = (u16*)(ws + 6291456);        // [1024][1024]
  u16*   w1T   = (u16*)(ws + 8388608);        // [4096][1024]
  u16*   w2T   = (u16*)(ws + 16777216);       // [1024][4096]
  float* bqkv  = (float*)(ws + 25165824);     // [3072]
  float* cosT  = (float*)(ws + 25178112);     // [2048][32]
  float* sinT  = (float*)(ws + 25440256);
  float* x2    = (float*)(ws + 25702400);     // [4096][1024] f32
  u16*   lnbuf = (u16*)(ws + 42479616);       // [4096][1024] bf16 (ln1/ln2)
  u16*   vtb   = lnbuf;                       // vt[32][64][2048] overlays lnbuf
  u16*   qkv   = (u16*)(ws + 50868224);       // [4096][3072] bf16
  u16*   attnO = (u16*)(ws + 76034048);       // [4096][1024] bf16
  u16*   hbuf  = qkv;                         // [4096][4096] bf16 overlays qkv+attnO

  const dim3 blk(256);
  // weights -> B^T bf16
  transpose_conv<<<dim3(16, 16), blk, 0, stream>>>(Wq, wqkvT, 1024, 1024);
  transpose_conv<<<dim3(16, 16), blk, 0, stream>>>(Wk, wqkvT + 1024 * 1024, 1024, 1024);
  transpose_conv<<<dim3(16, 16), blk, 0, stream>>>(Wv, wqkvT + 2048 * 1024, 1024, 1024);
  transpose_conv<<<dim3(16, 16), blk, 0, stream>>>(Wo, woT, 1024, 1024);
  transpose_conv<<<dim3(64, 16), blk, 0, stream>>>(W1, w1T, 1024, 4096);
  transpose_conv<<<dim3(16, 64), blk, 0, stream>>>(W2, w2T, 4096, 1024);
  concat_bias<<<12, blk, 0, stream>>>(bq, bk, bv, bqkv);
  rope_tables<<<256, blk, 0, stream>>>(cosT, sinT);

  // LN1 -> fused QKV GEMM -> RoPE -> V^T -> attention
  ln_kernel<<<NR_, blk, 0, stream>>>(x, ln1g, ln1b, lnbuf);
  gemm_bt<0><<<dim3(24, 32), blk, 0, stream>>>(lnbuf, wqkvT, bqkv, nullptr,
                                               qkv, NR_, 3072, 1024);
  rope_apply<<<2048, blk, 0, stream>>>(qkv, cosT, sinT);
  v_transpose<<<dim3(64, 32), blk, 0, stream>>>(qkv, vtb);
  attn_kernel<<<1024, blk, 0, stream>>>(qkv, vtb, attnO);

  // O-proj + residual (f32) -> LN2 -> MLP
  gemm_bt<2><<<dim3(8, 32), blk, 0, stream>>>(attnO, woT, bo, x, x2,
                                              NR_, 1024, 1024);
  ln_kernel<<<NR_, blk, 0, stream>>>(x2, ln2g, ln2b, lnbuf);
  gemm_bt<1><<<dim3(32, 32), blk, 0, stream>>>(lnbuf, w1T, b1, nullptr,
                                               hbuf, NR_, 4096, 1024);
  gemm_bt<2><<<dim3(8, 32), blk, 0, stream>>>(hbuf, w2T, b2, x2, out,
                                              NR_, 1024, 4096);
}

// Round 5
// 450.214 us; speedup vs baseline: 1.2837x; 1.0109x over previous
//
#include <hip/hip_runtime.h>
#include <math.h>

#define B_  2
#define L_  2048
#define D_  1024
#define H_  16
#define HD_ 64
#define DF_ 4096
#define NR_ 4096   // B_*L_

typedef __bf16 bf16_t;
typedef bf16_t bf16x8 __attribute__((ext_vector_type(8)));
typedef float  f32x4  __attribute__((ext_vector_type(4)));
typedef unsigned short u16;
typedef u16 u16x8 __attribute__((ext_vector_type(8)));
typedef u16 u16x4 __attribute__((ext_vector_type(4)));
typedef unsigned int u32;
typedef u32 u32x2 __attribute__((ext_vector_type(2)));

__device__ __forceinline__ u16 f2bf(float f) {
  unsigned u = __float_as_uint(f);
  u += 0x7fffu + ((u >> 16) & 1u);   // round-nearest-even
  return (u16)(u >> 16);
}
__device__ __forceinline__ float bf2f(u16 s) {
  return __uint_as_float(((unsigned)s) << 16);
}
__device__ __forceinline__ float gelu_f(float h) {
  return h * 0.5f * (1.f + tanhf(0.79788456f * h * (1.f + 0.044715f * h * h)));
}

// async global->LDS, 16B per lane. LDS dest must be wave-uniform-base + lane*16.
__device__ __forceinline__ void async_copy16(void* lds, const void* g) {
  __builtin_amdgcn_global_load_lds(
      (const __attribute__((address_space(1))) unsigned int*)g,
      (__attribute__((address_space(3))) unsigned int*)lds, 16, 0, 0);
}

// ---------------------------------------------------------------- transpose+bf16
// out[n][k] = bf16(W[k][n]);  W is [K][N] fp32 row-major, out is [N][K] bf16.
__global__ __launch_bounds__(256) void transpose_conv(
    const float* __restrict__ W, u16* __restrict__ out, int K, int N) {
  __shared__ float T[64][65];
  const int tid = threadIdx.x;
  const int n0 = blockIdx.x * 64, k0 = blockIdx.y * 64;
  const int r = tid >> 2, c4 = (tid & 3) * 16;
  const float* src = W + (size_t)(k0 + r) * N + n0 + c4;
#pragma unroll
  for (int i = 0; i < 16; i += 4) {
    float4 f = *(const float4*)(src + i);
    T[r][c4 + i + 0] = f.x; T[r][c4 + i + 1] = f.y;
    T[r][c4 + i + 2] = f.z; T[r][c4 + i + 3] = f.w;
  }
  __syncthreads();
  u16* dst = out + (size_t)(n0 + r) * K + k0 + c4;
#pragma unroll
  for (int half = 0; half < 2; ++half) {
    u16x8 o8;
#pragma unroll
    for (int i = 0; i < 8; ++i) o8[i] = f2bf(T[c4 + half * 8 + i][r]);
    *(u16x8*)(dst + half * 8) = o8;
  }
}

__global__ __launch_bounds__(256) void concat_bias(
    const float* __restrict__ bq, const float* __restrict__ bk,
    const float* __restrict__ bv, float* __restrict__ bqkv) {
  int i = blockIdx.x * 256 + threadIdx.x;
  if (i < 3072) {
    float v = (i < 1024) ? bq[i] : (i < 2048) ? bk[i - 1024] : bv[i - 2048];
    bqkv[i] = v;
  }
}

__global__ __launch_bounds__(256) void rope_tables(
    float* __restrict__ cosT, float* __restrict__ sinT) {
  int i = blockIdx.x * 256 + threadIdx.x;   // L_*32 total
  int pos = i >> 5, d = i & 31;
  float invf = powf(10000.f, -(float)d / 32.f);
  float a = (float)pos * invf;
  cosT[i] = cosf(a);
  sinT[i] = sinf(a);
}

// in-place RoPE on q,k halves of qkv[NR_][3072].
// q additionally scaled by log2(e)/8 (exp2-domain softmax + 1/sqrt(HD)).
__global__ __launch_bounds__(256) void rope_apply(
    u16* __restrict__ qkv, const float* __restrict__ cosT,
    const float* __restrict__ sinT) {
  int i = blockIdx.x * 256 + threadIdx.x;  // NR_*2*16*4 = 524288 threads
  int d0 = (i & 3) * 8;
  int hh = (i >> 2) & 15;
  int qk = (i >> 6) & 1;
  int row = i >> 7;
  int pos = row & (L_ - 1);
  size_t base = (size_t)row * 3072 + qk * 1024 + hh * 64 + d0;
  u16x8 a = *(const u16x8*)(qkv + base);
  u16x8 bb = *(const u16x8*)(qkv + base + 32);
  float4 c0 = *(const float4*)(cosT + pos * 32 + d0);
  float4 c1 = *(const float4*)(cosT + pos * 32 + d0 + 4);
  float4 s0 = *(const float4*)(sinT + pos * 32 + d0);
  float4 s1 = *(const float4*)(sinT + pos * 32 + d0 + 4);
  const float qs = qk ? 1.f : 0.18033688f;   // log2e/8 folded into Q
  u16x8 ra, rb;
#pragma unroll
  for (int j = 0; j < 8; ++j) {
    float co = (j < 4) ? ((const float*)&c0)[j] : ((const float*)&c1)[j - 4];
    float si = (j < 4) ? ((const float*)&s0)[j] : ((const float*)&s1)[j - 4];
    float v0 = bf2f(a[j]), v1 = bf2f(bb[j]);
    ra[j] = f2bf((v0 * co - v1 * si) * qs);
    rb[j] = f2bf((v1 * co + v0 * si) * qs);
  }
  *(u16x8*)(qkv + base) = ra;
  *(u16x8*)(qkv + base + 32) = rb;
}

// ---------------------------------------------------------------- V transpose
// vt[bh][d][seq] <- qkv V-part.
__global__ __launch_bounds__(256) void v_transpose(
    const u16* __restrict__ qkv, u16* __restrict__ vt) {
  const int tid = threadIdx.x;
  const int d = tid & 63, sub = tid >> 6;
  const int s0 = (blockIdx.x * 4 + sub) * 8;
  const int bh = blockIdx.y, b = bh >> 4, h = bh & 15;
  u16x8 o;
#pragma unroll
  for (int i = 0; i < 8; ++i)
    o[i] = qkv[(size_t)(b * L_ + s0 + i) * 3072 + 2048 + h * 64 + d];
  *(u16x8*)(vt + ((size_t)bh * 64 + d) * 2048 + s0) = o;
}

// ---------------------------------------------------------------- LayerNorm
__global__ __launch_bounds__(256) void ln_kernel(
    const float* __restrict__ x, const float* __restrict__ gm,
    const float* __restrict__ bt, u16* __restrict__ out) {
  const int row = blockIdx.x, tid = threadIdx.x;
  const float4 v = ((const float4*)(x + (size_t)row * D_))[tid];
  float s = v.x + v.y + v.z + v.w;
#pragma unroll
  for (int m = 1; m < 64; m <<= 1) s += __shfl_xor(s, m);
  __shared__ float red[4], red2[4];
  if ((tid & 63) == 0) red[tid >> 6] = s;
  __syncthreads();
  const float mean = (red[0] + red[1] + red[2] + red[3]) * (1.f / D_);
  float d0 = v.x - mean, d1 = v.y - mean, d2 = v.z - mean, d3 = v.w - mean;
  float sq = d0 * d0 + d1 * d1 + d2 * d2 + d3 * d3;
#pragma unroll
  for (int m = 1; m < 64; m <<= 1) sq += __shfl_xor(sq, m);
  if ((tid & 63) == 0) red2[tid >> 6] = sq;
  __syncthreads();
  const float var = (red2[0] + red2[1] + red2[2] + red2[3]) * (1.f / D_);
  const float rstd = rsqrtf(var + 1e-5f);
  const int c = tid * 4;
  u16x4 o;
  o[0] = f2bf(d0 * rstd * gm[c + 0] + bt[c + 0]);
  o[1] = f2bf(d1 * rstd * gm[c + 1] + bt[c + 1]);
  o[2] = f2bf(d2 * rstd * gm[c + 2] + bt[c + 2]);
  o[3] = f2bf(d3 * rstd * gm[c + 3] + bt[c + 3]);
  ((u16x4*)(out + (size_t)row * D_))[tid] = o;
}

// ---------------------------------------------------------------- GEMM
// C[M,N] = A[M,K] * Bt[N,K]^T (+bias[n]) ; EPI: 0=bf16, 1=gelu->bf16, 2=+resid->f32
// 1-D grid (nwg = gx*gy, %8==0), XCD-swizzled: each XCD gets a compact
// 8-m-row x n chunk for L2 reuse. Double-buffered LDS staging with counted
// vmcnt(4) + raw barriers (prefetch stays in flight across the barrier).
template <int EPI>
__global__ __launch_bounds__(256) void gemm_bt(
    const u16* __restrict__ A, const u16* __restrict__ Bt,
    const float* __restrict__ bias, const float* __restrict__ resid,
    void* __restrict__ out, int M, int N, int K, int gx) {
  __shared__ u16 As[2][128 * 32];
  __shared__ u16 Bs[2][128 * 32];
  const int tid = threadIdx.x;
  const int l = tid & 63, wid = tid >> 6;
  // XCD-aware remap: xcd = id&7 owns tiles [xcd*cpx, (xcd+1)*cpx) in an
  // 8-m-row-strip, n-inner-of-8 order -> compact rectangle per XCD.
  const int nwg = (int)gridDim.x, cpx = nwg >> 3;
  const int id = (int)blockIdx.x;
  const int wgid = (id & 7) * cpx + (id >> 3);
  const int strip = wgid / (8 * gx);
  const int rr = wgid - strip * 8 * gx;
  const int m0 = (strip * 8 + (rr & 7)) * 128;
  const int n0 = (rr >> 3) * 128;
  const int wr = wid >> 1, wc = wid & 1;
  const int r16 = l & 15, g = l >> 4;

  // staging geometry: tile = 128 rows x 64B; thread covers 16B at fo0 and fo0+4096
  const int fo0 = tid * 16;
  const int row0 = fo0 >> 6, ce0 = (fo0 & 63) >> 1;   // row, col-elements
  const u16* a_lo = A + (size_t)(m0 + row0) * K + ce0;
  const u16* a_hi = A + (size_t)(m0 + 64 + row0) * K + ce0;
  const u16* b_lo = Bt + (size_t)(n0 + row0) * K + ce0;
  const u16* b_hi = Bt + (size_t)(n0 + 64 + row0) * K + ce0;

#define STAGE_G(BUF, KB) do {                                   \
    async_copy16((char*)&As[BUF][0] + fo0, a_lo + (KB));        \
    async_copy16((char*)&As[BUF][0] + fo0 + 4096, a_hi + (KB)); \
    async_copy16((char*)&Bs[BUF][0] + fo0, b_lo + (KB));        \
    async_copy16((char*)&Bs[BUF][0] + fo0 + 4096, b_hi + (KB)); \
  } while (0)

  f32x4 acc[4][4];
#pragma unroll
  for (int mi = 0; mi < 4; ++mi)
#pragma unroll
    for (int ni = 0; ni < 4; ++ni) acc[mi][ni] = (f32x4){0.f, 0.f, 0.f, 0.f};

  const int nk = K >> 5;
  int buf = 0;
  STAGE_G(0, 0);
  for (int it = 0; it < nk; ++it) {
    const int nxt = ((it + 1 < nk) ? it + 1 : it) << 5;   // dummy restage on last
    STAGE_G(buf ^ 1, nxt);
    asm volatile("s_waitcnt vmcnt(4)" ::: "memory");   // current tile landed
    __builtin_amdgcn_s_barrier();

    const char* ab = (const char*)&As[buf][0];
    const char* bb = (const char*)&Bs[buf][0];
    bf16x8 ag[4], bg[4];
#pragma unroll
    for (int mi = 0; mi < 4; ++mi)
      ag[mi] = *(const bf16x8*)(ab + (wr * 64 + mi * 16 + r16) * 64 + g * 16);
#pragma unroll
    for (int ni = 0; ni < 4; ++ni)
      bg[ni] = *(const bf16x8*)(bb + (wc * 64 + ni * 16 + r16) * 64 + g * 16);
#pragma unroll
    for (int mi = 0; mi < 4; ++mi)
#pragma unroll
      for (int ni = 0; ni < 4; ++ni)
        acc[mi][ni] = __builtin_amdgcn_mfma_f32_16x16x32_bf16(
            ag[mi], bg[ni], acc[mi][ni], 0, 0, 0);

    __builtin_amdgcn_s_barrier();   // all waves done reading buf
    buf ^= 1;
  }
#undef STAGE_G

  const int cl = r16, rq = g;
#pragma unroll
  for (int ni = 0; ni < 4; ++ni) {
    const int col = n0 + wc * 64 + ni * 16 + cl;
    const float bv = bias[col];
#pragma unroll
    for (int mi = 0; mi < 4; ++mi) {
#pragma unroll
      for (int j = 0; j < 4; ++j) {
        const int rowg = m0 + wr * 64 + mi * 16 + rq * 4 + j;
        float v = acc[mi][ni][j] + bv;
        if (EPI == 0) {
          ((u16*)out)[(size_t)rowg * N + col] = f2bf(v);
        } else if (EPI == 1) {
          ((u16*)out)[(size_t)rowg * N + col] = f2bf(gelu_f(v));
        } else {
          ((float*)out)[(size_t)rowg * N + col] =
              v + resid[(size_t)rowg * N + col];
        }
      }
    }
  }
}

// ---------------------------------------------------------------- flash attention
// LDS-staged K/V shared by 4 waves, double-buffered via global_load_lds with
// counted vmcnt (never drained) + raw s_barrier. Swapped-operand in-register
// softmax (lane owns a q-row); per-wave P in LDS; exp2 domain.
// XOR-swizzled K/V LDS layout via pre-swizzled global source addresses.
__global__ __launch_bounds__(256, 4) void attn_kernel(
    const u16* __restrict__ qkv, const u16* __restrict__ vt,
    u16* __restrict__ o) {
  const int tid = threadIdx.x, l = tid & 63, wid = tid >> 6;
  // XCD-aware decomposition: heavy q-blocks first.
  const int id = blockIdx.x;
  const int seq = id >> 3, xcd = id & 7;
  const int bh = xcd * 4 + (seq & 3);
  const int qblk = 31 - (seq >> 2);
  const int b = bh >> 4, h = bh & 15;
  const int q0 = qblk * 64;

  __shared__ u16 Ks[2][64 * 64];   // [kvrow][d], 128B rows, XOR-swizzled
  __shared__ u16 Vs[2][64 * 64];   // [d][kvseq], 128B rows, XOR-swizzled
  __shared__ u16 Ps[4][16 * 64];   // per-wave P[qrow][kcol], swizzled

  const int r16 = l & 15, g = l >> 4;

  // staging geometry: chunk c = tid (+256), row = c>>3, colb = (c&7)*16.
  // source column pre-swizzled so LDS linear layout == swizzled layout.
  const int srow = tid >> 3, scb = (tid & 7) * 16;
  const int scol = (scb ^ ((srow & 7) << 4)) >> 1;   // element offset in row
  const u16* ksrc = qkv + (size_t)(b * L_ + srow) * 3072 + 1024 + h * 64 + scol;
  const u16* vsrc = vt + ((size_t)bh * 64 + srow) * 2048 + scol;

#define STAGE_KV(BUF, KB) do {                                              \
    async_copy16((char*)&Ks[BUF][0] + tid * 16,                             \
                 ksrc + (size_t)(KB) * 3072);                               \
    async_copy16((char*)&Ks[BUF][0] + tid * 16 + 4096,                      \
                 ksrc + (size_t)(KB) * 3072 + 32 * 3072);                   \
    async_copy16((char*)&Vs[BUF][0] + tid * 16, vsrc + (KB));               \
    async_copy16((char*)&Vs[BUF][0] + tid * 16 + 4096,                      \
                 vsrc + (KB) + 32 * 2048);                                  \
  } while (0)

  // Q B-fragments: B[col=qrow=r16][k=d-slice]; q pre-scaled (log2e/8) + roped.
  const int qrow_g = b * L_ + q0 + wid * 16 + r16;
  const u16* qp = qkv + (size_t)qrow_g * 3072 + h * 64 + g * 8;
  const bf16x8 qb0 = *(const bf16x8*)qp;
  const bf16x8 qb1 = *(const bf16x8*)(qp + 32);

  float m_ = -1e30f, ls = 0.f;
  f32x4 oa[4];
#pragma unroll
  for (int t = 0; t < 4; ++t) oa[t] = (f32x4){0.f, 0.f, 0.f, 0.f};

  char* const psw = (char*)&Ps[wid][0] + r16 * 128;
  const int pswz = (r16 & 7) << 4;

  const int nt = qblk + 1;
  int buf = 0;
  STAGE_KV(0, 0);

  for (int it = 0; it < nt; ++it) {
    const int kb = it * 64;
    const bool diag = (it == nt - 1);
    STAGE_KV(buf ^ 1, diag ? kb : kb + 64);      // uniform 4 loads (dummy on last)
    asm volatile("s_waitcnt vmcnt(4)" ::: "memory");  // cur staged; next in flight
    __builtin_amdgcn_s_barrier();

    const char* kb_l = (const char*)&Ks[0][0] + buf * 8192;
    const char* vb_l = (const char*)&Vs[0][0] + buf * 8192;

    // ---- S^T = K Q^T : lane holds p[t][j] = S[kcol=t*16+g*4+j][qrow=r16]
    float p[4][4];
#pragma unroll
    for (int t = 0; t < 4; ++t) {
      if (diag && t > wid) {     // fully-masked sub-tile: skip MFMA
#pragma unroll
        for (int j = 0; j < 4; ++j) p[t][j] = -1e30f;
        continue;
      }
      const int krow = t * 16 + r16, swzk = (krow & 7) << 4;
      bf16x8 k0 = *(const bf16x8*)(kb_l + krow * 128 + ((g * 16) ^ swzk));
      bf16x8 k1 = *(const bf16x8*)(kb_l + krow * 128 + ((64 + g * 16) ^ swzk));
      f32x4 s = (f32x4){0.f, 0.f, 0.f, 0.f};
      s = __builtin_amdgcn_mfma_f32_16x16x32_bf16(k0, qb0, s, 0, 0, 0);
      s = __builtin_amdgcn_mfma_f32_16x16x32_bf16(k1, qb1, s, 0, 0, 0);
      if (diag && t == wid) {
#pragma unroll
        for (int j = 0; j < 4; ++j)
          p[t][j] = (g * 4 + j <= r16) ? s[j] : -1e30f;
      } else {
#pragma unroll
        for (int j = 0; j < 4; ++j) p[t][j] = s[j];
      }
    }

    // ---- online softmax: per-lane row, 4 cross-lane shuffles total
    float pm = -1e30f;
#pragma unroll
    for (int t = 0; t < 4; ++t)
#pragma unroll
      for (int j = 0; j < 4; ++j) pm = fmaxf(pm, p[t][j]);
    pm = fmaxf(pm, __shfl_xor(pm, 16));
    pm = fmaxf(pm, __shfl_xor(pm, 32));
    const float mn = fmaxf(m_, pm);
    const float sc = exp2f(m_ - mn);
    float rs = 0.f;
#pragma unroll
    for (int t = 0; t < 4; ++t)
#pragma unroll
      for (int j = 0; j < 4; ++j) { p[t][j] = exp2f(p[t][j] - mn); rs += p[t][j]; }
    rs += __shfl_xor(rs, 16);
    rs += __shfl_xor(rs, 32);
    ls = ls * sc + rs;
    m_ = mn;
#pragma unroll
    for (int t = 0; t < 4; ++t) oa[t] *= sc;

    // ---- P -> per-wave LDS (bf16, 4x b64 writes, swizzled)
#pragma unroll
    for (int t = 0; t < 4; ++t) {
      u32x2 w;
      w[0] = (u32)f2bf(p[t][0]) | ((u32)f2bf(p[t][1]) << 16);
      w[1] = (u32)f2bf(p[t][2]) | ((u32)f2bf(p[t][3]) << 16);
      *(u32x2*)(psw + ((t * 32 + g * 8) ^ pswz)) = w;
    }

    // ---- O^T += V^T P : oa[t][j] = O[d=t*16+g*4+j][qrow=r16]
#pragma unroll
    for (int kc = 0; kc < 2; ++kc) {
      bf16x8 pf = *(const bf16x8*)(psw + ((kc * 64 + g * 16) ^ pswz));
#pragma unroll
      for (int t = 0; t < 4; ++t) {
        const int vrow = t * 16 + r16, swzv = (vrow & 7) << 4;
        bf16x8 vf = *(const bf16x8*)(vb_l + vrow * 128 +
                                     ((kc * 64 + g * 16) ^ swzv));
        oa[t] = __builtin_amdgcn_mfma_f32_16x16x32_bf16(vf, pf, oa[t], 0, 0, 0);
      }
    }

    __builtin_amdgcn_s_barrier();   // all waves done reading buf
    buf ^= 1;
  }
#undef STAGE_KV

  // ---- normalize + store (per-lane 1/ls, no shuffles)
  const float inv = 1.f / ls;
  u16* op = o + (size_t)qrow_g * D_ + h * 64;
#pragma unroll
  for (int t = 0; t < 4; ++t)
#pragma unroll
    for (int j = 0; j < 4; ++j)
      op[t * 16 + g * 4 + j] = f2bf(oa[t][j] * inv);
}

// ---------------------------------------------------------------- launch
extern "C" void kernel_launch(void* const* d_in, const int* in_sizes, int n_in,
                              void* d_out, int out_size, void* d_ws, size_t ws_size,
                              hipStream_t stream) {
  (void)in_sizes; (void)n_in; (void)out_size; (void)ws_size;
  const float* x    = (const float*)d_in[0];
  const float* Wq   = (const float*)d_in[2];
  const float* bq   = (const float*)d_in[3];
  const float* Wk   = (const float*)d_in[4];
  const float* bk   = (const float*)d_in[5];
  const float* Wv   = (const float*)d_in[6];
  const float* bv   = (const float*)d_in[7];
  const float* Wo   = (const float*)d_in[8];
  const float* bo   = (const float*)d_in[9];
  const float* ln1g = (const float*)d_in[10];
  const float* ln1b = (const float*)d_in[11];
  const float* W1   = (const float*)d_in[12];
  const float* b1   = (const float*)d_in[13];
  const float* W2   = (const float*)d_in[14];
  const float* b2   = (const float*)d_in[15];
  const float* ln2g = (const float*)d_in[16];
  const float* ln2b = (const float*)d_in[17];
  float* out = (float*)d_out;
  char* ws = (char*)d_ws;

  u16*   wqkvT = (u16*)(ws + 0);              // [3072][1024] bf16
  u16*   woT   = (u16*)(ws + 6291456);        // [1024][1024]
  u16*   w1T   = (u16*)(ws + 8388608);        // [4096][1024]
  u16*   w2T   = (u16*)(ws + 16777216);       // [1024][4096]
  float* bqkv  = (float*)(ws + 25165824);     // [3072]
  float* cosT  = (float*)(ws + 25178112);     // [2048][32]
  float* sinT  = (float*)(ws + 25440256);
  float* x2    = (float*)(ws + 25702400);     // [4096][1024] f32
  u16*   lnbuf = (u16*)(ws + 42479616);       // [4096][1024] bf16 (ln1/ln2)
  u16*   vtb   = lnbuf;                       // vt[32][64][2048] overlays lnbuf
  u16*   qkv   = (u16*)(ws + 50868224);       // [4096][3072] bf16
  u16*   attnO = (u16*)(ws + 76034048);       // [4096][1024] bf16
  u16*   hbuf  = qkv;                         // [4096][4096] bf16 overlays qkv+attnO

  const dim3 blk(256);
  // weights -> B^T bf16
  transpose_conv<<<dim3(16, 16), blk, 0, stream>>>(Wq, wqkvT, 1024, 1024);
  transpose_conv<<<dim3(16, 16), blk, 0, stream>>>(Wk, wqkvT + 1024 * 1024, 1024, 1024);
  transpose_conv<<<dim3(16, 16), blk, 0, stream>>>(Wv, wqkvT + 2048 * 1024, 1024, 1024);
  transpose_conv<<<dim3(16, 16), blk, 0, stream>>>(Wo, woT, 1024, 1024);
  transpose_conv<<<dim3(64, 16), blk, 0, stream>>>(W1, w1T, 1024, 4096);
  transpose_conv<<<dim3(16, 64), blk, 0, stream>>>(W2, w2T, 4096, 1024);
  concat_bias<<<12, blk, 0, stream>>>(bq, bk, bv, bqkv);
  rope_tables<<<256, blk, 0, stream>>>(cosT, sinT);

  // LN1 -> fused QKV GEMM -> RoPE -> V^T -> attention
  ln_kernel<<<NR_, blk, 0, stream>>>(x, ln1g, ln1b, lnbuf);
  gemm_bt<0><<<768, blk, 0, stream>>>(lnbuf, wqkvT, bqkv, nullptr,
                                      qkv, NR_, 3072, 1024, 24);
  rope_apply<<<2048, blk, 0, stream>>>(qkv, cosT, sinT);
  v_transpose<<<dim3(64, 32), blk, 0, stream>>>(qkv, vtb);
  attn_kernel<<<1024, blk, 0, stream>>>(qkv, vtb, attnO);

  // O-proj + residual (f32) -> LN2 -> MLP
  gemm_bt<2><<<256, blk, 0, stream>>>(attnO, woT, bo, x, x2,
                                      NR_, 1024, 1024, 8);
  ln_kernel<<<NR_, blk, 0, stream>>>(x2, ln2g, ln2b, lnbuf);
  gemm_bt<1><<<1024, blk, 0, stream>>>(lnbuf, w1T, b1, nullptr,
                                       hbuf, NR_, 4096, 1024, 32);
  gemm_bt<2><<<256, blk, 0, stream>>>(hbuf, w2T, b2, x2, out,
                                      NR_, 1024, 4096, 8);
}

// Round 6
// 446.261 us; speedup vs baseline: 1.2951x; 1.0089x over previous
//
#include <hip/hip_runtime.h>
#include <math.h>

#define B_  2
#define L_  2048
#define D_  1024
#define H_  16
#define HD_ 64
#define DF_ 4096
#define NR_ 4096   // B_*L_

typedef __bf16 bf16_t;
typedef bf16_t bf16x8 __attribute__((ext_vector_type(8)));
typedef float  f32x4  __attribute__((ext_vector_type(4)));
typedef unsigned short u16;
typedef u16 u16x8 __attribute__((ext_vector_type(8)));
typedef u16 u16x4 __attribute__((ext_vector_type(4)));
typedef unsigned int u32;
typedef u32 u32x2 __attribute__((ext_vector_type(2)));

__device__ __forceinline__ u16 f2bf(float f) {
  unsigned u = __float_as_uint(f);
  u += 0x7fffu + ((u >> 16) & 1u);   // round-nearest-even
  return (u16)(u >> 16);
}
__device__ __forceinline__ float bf2f(u16 s) {
  return __uint_as_float(((unsigned)s) << 16);
}
__device__ __forceinline__ float gelu_f(float h) {
  return h * 0.5f * (1.f + tanhf(0.79788456f * h * (1.f + 0.044715f * h * h)));
}

// async global->LDS, 16B per lane. LDS dest must be wave-uniform-base + lane*16.
__device__ __forceinline__ void async_copy16(void* lds, const void* g) {
  __builtin_amdgcn_global_load_lds(
      (const __attribute__((address_space(1))) unsigned int*)g,
      (__attribute__((address_space(3))) unsigned int*)lds, 16, 0, 0);
}

// ---------------------------------------------------------------- transpose+bf16
// out[n][k] = bf16(W[k][n]);  W is [K][N] fp32 row-major, out is [N][K] bf16.
__global__ __launch_bounds__(256) void transpose_conv(
    const float* __restrict__ W, u16* __restrict__ out, int K, int N) {
  __shared__ float T[64][65];
  const int tid = threadIdx.x;
  const int n0 = blockIdx.x * 64, k0 = blockIdx.y * 64;
  const int r = tid >> 2, c4 = (tid & 3) * 16;
  const float* src = W + (size_t)(k0 + r) * N + n0 + c4;
#pragma unroll
  for (int i = 0; i < 16; i += 4) {
    float4 f = *(const float4*)(src + i);
    T[r][c4 + i + 0] = f.x; T[r][c4 + i + 1] = f.y;
    T[r][c4 + i + 2] = f.z; T[r][c4 + i + 3] = f.w;
  }
  __syncthreads();
  u16* dst = out + (size_t)(n0 + r) * K + k0 + c4;
#pragma unroll
  for (int half = 0; half < 2; ++half) {
    u16x8 o8;
#pragma unroll
    for (int i = 0; i < 8; ++i) o8[i] = f2bf(T[c4 + half * 8 + i][r]);
    *(u16x8*)(dst + half * 8) = o8;
  }
}

__global__ __launch_bounds__(256) void concat_bias(
    const float* __restrict__ bq, const float* __restrict__ bk,
    const float* __restrict__ bv, float* __restrict__ bqkv) {
  int i = blockIdx.x * 256 + threadIdx.x;
  if (i < 3072) {
    float v = (i < 1024) ? bq[i] : (i < 2048) ? bk[i - 1024] : bv[i - 2048];
    bqkv[i] = v;
  }
}

__global__ __launch_bounds__(256) void rope_tables(
    float* __restrict__ cosT, float* __restrict__ sinT) {
  int i = blockIdx.x * 256 + threadIdx.x;   // L_*32 total
  int pos = i >> 5, d = i & 31;
  float invf = powf(10000.f, -(float)d / 32.f);
  float a = (float)pos * invf;
  cosT[i] = cosf(a);
  sinT[i] = sinf(a);
}

// in-place RoPE on q,k halves of qkv[NR_][3072].
// q additionally scaled by log2(e)/8 (exp2-domain softmax + 1/sqrt(HD)).
__global__ __launch_bounds__(256) void rope_apply(
    u16* __restrict__ qkv, const float* __restrict__ cosT,
    const float* __restrict__ sinT) {
  int i = blockIdx.x * 256 + threadIdx.x;  // NR_*2*16*4 = 524288 threads
  int d0 = (i & 3) * 8;
  int hh = (i >> 2) & 15;
  int qk = (i >> 6) & 1;
  int row = i >> 7;
  int pos = row & (L_ - 1);
  size_t base = (size_t)row * 3072 + qk * 1024 + hh * 64 + d0;
  u16x8 a = *(const u16x8*)(qkv + base);
  u16x8 bb = *(const u16x8*)(qkv + base + 32);
  float4 c0 = *(const float4*)(cosT + pos * 32 + d0);
  float4 c1 = *(const float4*)(cosT + pos * 32 + d0 + 4);
  float4 s0 = *(const float4*)(sinT + pos * 32 + d0);
  float4 s1 = *(const float4*)(sinT + pos * 32 + d0 + 4);
  const float qs = qk ? 1.f : 0.18033688f;   // log2e/8 folded into Q
  u16x8 ra, rb;
#pragma unroll
  for (int j = 0; j < 8; ++j) {
    float co = (j < 4) ? ((const float*)&c0)[j] : ((const float*)&c1)[j - 4];
    float si = (j < 4) ? ((const float*)&s0)[j] : ((const float*)&s1)[j - 4];
    float v0 = bf2f(a[j]), v1 = bf2f(bb[j]);
    ra[j] = f2bf((v0 * co - v1 * si) * qs);
    rb[j] = f2bf((v1 * co + v0 * si) * qs);
  }
  *(u16x8*)(qkv + base) = ra;
  *(u16x8*)(qkv + base + 32) = rb;
}

// ---------------------------------------------------------------- V transpose
// vt[bh][d][seq] <- qkv V-part.
__global__ __launch_bounds__(256) void v_transpose(
    const u16* __restrict__ qkv, u16* __restrict__ vt) {
  const int tid = threadIdx.x;
  const int d = tid & 63, sub = tid >> 6;
  const int s0 = (blockIdx.x * 4 + sub) * 8;
  const int bh = blockIdx.y, b = bh >> 4, h = bh & 15;
  u16x8 o;
#pragma unroll
  for (int i = 0; i < 8; ++i)
    o[i] = qkv[(size_t)(b * L_ + s0 + i) * 3072 + 2048 + h * 64 + d];
  *(u16x8*)(vt + ((size_t)bh * 64 + d) * 2048 + s0) = o;
}

// ---------------------------------------------------------------- LayerNorm
__global__ __launch_bounds__(256) void ln_kernel(
    const float* __restrict__ x, const float* __restrict__ gm,
    const float* __restrict__ bt, u16* __restrict__ out) {
  const int row = blockIdx.x, tid = threadIdx.x;
  const float4 v = ((const float4*)(x + (size_t)row * D_))[tid];
  float s = v.x + v.y + v.z + v.w;
#pragma unroll
  for (int m = 1; m < 64; m <<= 1) s += __shfl_xor(s, m);
  __shared__ float red[4], red2[4];
  if ((tid & 63) == 0) red[tid >> 6] = s;
  __syncthreads();
  const float mean = (red[0] + red[1] + red[2] + red[3]) * (1.f / D_);
  float d0 = v.x - mean, d1 = v.y - mean, d2 = v.z - mean, d3 = v.w - mean;
  float sq = d0 * d0 + d1 * d1 + d2 * d2 + d3 * d3;
#pragma unroll
  for (int m = 1; m < 64; m <<= 1) sq += __shfl_xor(sq, m);
  if ((tid & 63) == 0) red2[tid >> 6] = sq;
  __syncthreads();
  const float var = (red2[0] + red2[1] + red2[2] + red2[3]) * (1.f / D_);
  const float rstd = rsqrtf(var + 1e-5f);
  const int c = tid * 4;
  u16x4 o;
  o[0] = f2bf(d0 * rstd * gm[c + 0] + bt[c + 0]);
  o[1] = f2bf(d1 * rstd * gm[c + 1] + bt[c + 1]);
  o[2] = f2bf(d2 * rstd * gm[c + 2] + bt[c + 2]);
  o[3] = f2bf(d3 * rstd * gm[c + 3] + bt[c + 3]);
  ((u16x4*)(out + (size_t)row * D_))[tid] = o;
}

// ---------------------------------------------------------------- GEMM
// C[M,N] = A[M,K] * Bt[N,K]^T (+bias[n]) ; EPI: 0=bf16, 1=gelu->bf16, 2=+resid->f32
// XCD-swizzled 1-D grid; double-buffered LDS staging with counted vmcnt(4).
// LDS tiles XOR-swizzled (byte ^= ((row>>1)&3)<<4) -> fragment ds_read_b128
// hits the free 2-way bank minimum (was 8-way). Source pre-swizzled to match.
template <int EPI>
__global__ __launch_bounds__(256) void gemm_bt(
    const u16* __restrict__ A, const u16* __restrict__ Bt,
    const float* __restrict__ bias, const float* __restrict__ resid,
    void* __restrict__ out, int M, int N, int K, int gx) {
  __shared__ u16 As[2][128 * 32];
  __shared__ u16 Bs[2][128 * 32];
  const int tid = threadIdx.x;
  const int l = tid & 63, wid = tid >> 6;
  // XCD-aware remap: xcd = id&7 owns a compact 8-m-row x n rectangle.
  const int nwg = (int)gridDim.x, cpx = nwg >> 3;
  const int id = (int)blockIdx.x;
  const int wgid = (id & 7) * cpx + (id >> 3);
  const int strip = wgid / (8 * gx);
  const int rr = wgid - strip * 8 * gx;
  const int m0 = (strip * 8 + (rr & 7)) * 128;
  const int n0 = (rr >> 3) * 128;
  const int wr = wid >> 1, wc = wid & 1;
  const int r16 = l & 15, g = l >> 4;

  // staging: thread covers 16B at fo0 (rows 0..63) and fo0+4096 (rows 64..127).
  // Source col pre-swizzled so linear LDS == swizzled layout (involution).
  const int fo0 = tid * 16;
  const int row0 = fo0 >> 6;
  const int scol = ((fo0 & 63) ^ (((row0 >> 1) & 3) << 4)) >> 1;
  const u16* a_lo = A + (size_t)(m0 + row0) * K + scol;
  const u16* a_hi = A + (size_t)(m0 + 64 + row0) * K + scol;   // same swz: (64+row)>>1 &3 == row>>1 &3
  const u16* b_lo = Bt + (size_t)(n0 + row0) * K + scol;
  const u16* b_hi = Bt + (size_t)(n0 + 64 + row0) * K + scol;

#define STAGE_G(BUF, KB) do {                                   \
    async_copy16((char*)&As[BUF][0] + fo0, a_lo + (KB));        \
    async_copy16((char*)&As[BUF][0] + fo0 + 4096, a_hi + (KB)); \
    async_copy16((char*)&Bs[BUF][0] + fo0, b_lo + (KB));        \
    async_copy16((char*)&Bs[BUF][0] + fo0 + 4096, b_hi + (KB)); \
  } while (0)

  f32x4 acc[4][4];
#pragma unroll
  for (int mi = 0; mi < 4; ++mi)
#pragma unroll
    for (int ni = 0; ni < 4; ++ni) acc[mi][ni] = (f32x4){0.f, 0.f, 0.f, 0.f};

  // per-lane fragment-read byte column (swizzled): swz depends only on r16.
  const int fcol = (g * 16) ^ (((r16 >> 1) & 3) << 4);

  const int nk = K >> 5;
  int buf = 0;
  STAGE_G(0, 0);
  for (int it = 0; it < nk; ++it) {
    const int nxt = ((it + 1 < nk) ? it + 1 : it) << 5;   // dummy restage on last
    STAGE_G(buf ^ 1, nxt);
    asm volatile("s_waitcnt vmcnt(4)" ::: "memory");   // current tile landed
    __builtin_amdgcn_s_barrier();

    const char* ab = (const char*)&As[buf][0];
    const char* bb = (const char*)&Bs[buf][0];
    bf16x8 ag[4], bg[4];
#pragma unroll
    for (int mi = 0; mi < 4; ++mi)
      ag[mi] = *(const bf16x8*)(ab + (wr * 64 + mi * 16 + r16) * 64 + fcol);
#pragma unroll
    for (int ni = 0; ni < 4; ++ni)
      bg[ni] = *(const bf16x8*)(bb + (wc * 64 + ni * 16 + r16) * 64 + fcol);
#pragma unroll
    for (int mi = 0; mi < 4; ++mi)
#pragma unroll
      for (int ni = 0; ni < 4; ++ni)
        acc[mi][ni] = __builtin_amdgcn_mfma_f32_16x16x32_bf16(
            ag[mi], bg[ni], acc[mi][ni], 0, 0, 0);

    __builtin_amdgcn_s_barrier();   // all waves done reading buf
    buf ^= 1;
  }
#undef STAGE_G

  const int cl = r16, rq = g;
#pragma unroll
  for (int ni = 0; ni < 4; ++ni) {
    const int col = n0 + wc * 64 + ni * 16 + cl;
    const float bv = bias[col];
#pragma unroll
    for (int mi = 0; mi < 4; ++mi) {
#pragma unroll
      for (int j = 0; j < 4; ++j) {
        const int rowg = m0 + wr * 64 + mi * 16 + rq * 4 + j;
        float v = acc[mi][ni][j] + bv;
        if (EPI == 0) {
          ((u16*)out)[(size_t)rowg * N + col] = f2bf(v);
        } else if (EPI == 1) {
          ((u16*)out)[(size_t)rowg * N + col] = f2bf(gelu_f(v));
        } else {
          ((float*)out)[(size_t)rowg * N + col] =
              v + resid[(size_t)rowg * N + col];
        }
      }
    }
  }
}

// ---------------------------------------------------------------- flash attention
// LDS-staged K/V shared by 4 waves, double-buffered via global_load_lds with
// counted vmcnt (never drained) + raw s_barrier. Swapped-operand in-register
// softmax (lane owns a q-row); per-wave P in LDS; exp2 domain.
// XOR-swizzled K/V LDS layout via pre-swizzled global source addresses.
__global__ __launch_bounds__(256, 4) void attn_kernel(
    const u16* __restrict__ qkv, const u16* __restrict__ vt,
    u16* __restrict__ o) {
  const int tid = threadIdx.x, l = tid & 63, wid = tid >> 6;
  // XCD-aware decomposition: heavy q-blocks first.
  const int id = blockIdx.x;
  const int seq = id >> 3, xcd = id & 7;
  const int bh = xcd * 4 + (seq & 3);
  const int qblk = 31 - (seq >> 2);
  const int b = bh >> 4, h = bh & 15;
  const int q0 = qblk * 64;

  __shared__ u16 Ks[2][64 * 64];   // [kvrow][d], 128B rows, XOR-swizzled
  __shared__ u16 Vs[2][64 * 64];   // [d][kvseq], 128B rows, XOR-swizzled
  __shared__ u16 Ps[4][16 * 64];   // per-wave P[qrow][kcol], swizzled

  const int r16 = l & 15, g = l >> 4;

  // staging geometry: chunk c = tid (+256), row = c>>3, colb = (c&7)*16.
  // source column pre-swizzled so LDS linear layout == swizzled layout.
  const int srow = tid >> 3, scb = (tid & 7) * 16;
  const int scol = (scb ^ ((srow & 7) << 4)) >> 1;   // element offset in row
  const u16* ksrc = qkv + (size_t)(b * L_ + srow) * 3072 + 1024 + h * 64 + scol;
  const u16* vsrc = vt + ((size_t)bh * 64 + srow) * 2048 + scol;

#define STAGE_KV(BUF, KB) do {                                              \
    async_copy16((char*)&Ks[BUF][0] + tid * 16,                             \
                 ksrc + (size_t)(KB) * 3072);                               \
    async_copy16((char*)&Ks[BUF][0] + tid * 16 + 4096,                      \
                 ksrc + (size_t)(KB) * 3072 + 32 * 3072);                   \
    async_copy16((char*)&Vs[BUF][0] + tid * 16, vsrc + (KB));               \
    async_copy16((char*)&Vs[BUF][0] + tid * 16 + 4096,                      \
                 vsrc + (KB) + 32 * 2048);                                  \
  } while (0)

  // Q B-fragments: B[col=qrow=r16][k=d-slice]; q pre-scaled (log2e/8) + roped.
  const int qrow_g = b * L_ + q0 + wid * 16 + r16;
  const u16* qp = qkv + (size_t)qrow_g * 3072 + h * 64 + g * 8;
  const bf16x8 qb0 = *(const bf16x8*)qp;
  const bf16x8 qb1 = *(const bf16x8*)(qp + 32);

  float m_ = -1e30f, ls = 0.f;
  f32x4 oa[4];
#pragma unroll
  for (int t = 0; t < 4; ++t) oa[t] = (f32x4){0.f, 0.f, 0.f, 0.f};

  char* const psw = (char*)&Ps[wid][0] + r16 * 128;
  const int pswz = (r16 & 7) << 4;

  const int nt = qblk + 1;
  int buf = 0;
  STAGE_KV(0, 0);

  for (int it = 0; it < nt; ++it) {
    const int kb = it * 64;
    const bool diag = (it == nt - 1);
    STAGE_KV(buf ^ 1, diag ? kb : kb + 64);      // uniform 4 loads (dummy on last)
    asm volatile("s_waitcnt vmcnt(4)" ::: "memory");  // cur staged; next in flight
    __builtin_amdgcn_s_barrier();

    const char* kb_l = (const char*)&Ks[0][0] + buf * 8192;
    const char* vb_l = (const char*)&Vs[0][0] + buf * 8192;

    // ---- S^T = K Q^T : lane holds p[t][j] = S[kcol=t*16+g*4+j][qrow=r16]
    float p[4][4];
#pragma unroll
    for (int t = 0; t < 4; ++t) {
      if (diag && t > wid) {     // fully-masked sub-tile: skip MFMA
#pragma unroll
        for (int j = 0; j < 4; ++j) p[t][j] = -1e30f;
        continue;
      }
      const int krow = t * 16 + r16, swzk = (krow & 7) << 4;
      bf16x8 k0 = *(const bf16x8*)(kb_l + krow * 128 + ((g * 16) ^ swzk));
      bf16x8 k1 = *(const bf16x8*)(kb_l + krow * 128 + ((64 + g * 16) ^ swzk));
      f32x4 s = (f32x4){0.f, 0.f, 0.f, 0.f};
      s = __builtin_amdgcn_mfma_f32_16x16x32_bf16(k0, qb0, s, 0, 0, 0);
      s = __builtin_amdgcn_mfma_f32_16x16x32_bf16(k1, qb1, s, 0, 0, 0);
      if (diag && t == wid) {
#pragma unroll
        for (int j = 0; j < 4; ++j)
          p[t][j] = (g * 4 + j <= r16) ? s[j] : -1e30f;
      } else {
#pragma unroll
        for (int j = 0; j < 4; ++j) p[t][j] = s[j];
      }
    }

    // ---- online softmax: per-lane row, 4 cross-lane shuffles total
    float pm = -1e30f;
#pragma unroll
    for (int t = 0; t < 4; ++t)
#pragma unroll
      for (int j = 0; j < 4; ++j) pm = fmaxf(pm, p[t][j]);
    pm = fmaxf(pm, __shfl_xor(pm, 16));
    pm = fmaxf(pm, __shfl_xor(pm, 32));
    const float mn = fmaxf(m_, pm);
    const float sc = exp2f(m_ - mn);
    float rs = 0.f;
#pragma unroll
    for (int t = 0; t < 4; ++t)
#pragma unroll
      for (int j = 0; j < 4; ++j) { p[t][j] = exp2f(p[t][j] - mn); rs += p[t][j]; }
    rs += __shfl_xor(rs, 16);
    rs += __shfl_xor(rs, 32);
    ls = ls * sc + rs;
    m_ = mn;
#pragma unroll
    for (int t = 0; t < 4; ++t) oa[t] *= sc;

    // ---- P -> per-wave LDS (bf16, 4x b64 writes, swizzled)
#pragma unroll
    for (int t = 0; t < 4; ++t) {
      u32x2 w;
      w[0] = (u32)f2bf(p[t][0]) | ((u32)f2bf(p[t][1]) << 16);
      w[1] = (u32)f2bf(p[t][2]) | ((u32)f2bf(p[t][3]) << 16);
      *(u32x2*)(psw + ((t * 32 + g * 8) ^ pswz)) = w;
    }

    // ---- O^T += V^T P : oa[t][j] = O[d=t*16+g*4+j][qrow=r16]
#pragma unroll
    for (int kc = 0; kc < 2; ++kc) {
      bf16x8 pf = *(const bf16x8*)(psw + ((kc * 64 + g * 16) ^ pswz));
#pragma unroll
      for (int t = 0; t < 4; ++t) {
        const int vrow = t * 16 + r16, swzv = (vrow & 7) << 4;
        bf16x8 vf = *(const bf16x8*)(vb_l + vrow * 128 +
                                     ((kc * 64 + g * 16) ^ swzv));
        oa[t] = __builtin_amdgcn_mfma_f32_16x16x32_bf16(vf, pf, oa[t], 0, 0, 0);
      }
    }

    __builtin_amdgcn_s_barrier();   // all waves done reading buf
    buf ^= 1;
  }
#undef STAGE_KV

  // ---- normalize + store (per-lane 1/ls, no shuffles)
  const float inv = 1.f / ls;
  u16* op = o + (size_t)qrow_g * D_ + h * 64;
#pragma unroll
  for (int t = 0; t < 4; ++t)
#pragma unroll
    for (int j = 0; j < 4; ++j)
      op[t * 16 + g * 4 + j] = f2bf(oa[t][j] * inv);
}

// ---------------------------------------------------------------- launch
extern "C" void kernel_launch(void* const* d_in, const int* in_sizes, int n_in,
                              void* d_out, int out_size, void* d_ws, size_t ws_size,
                              hipStream_t stream) {
  (void)in_sizes; (void)n_in; (void)out_size; (void)ws_size;
  const float* x    = (const float*)d_in[0];
  const float* Wq   = (const float*)d_in[2];
  const float* bq   = (const float*)d_in[3];
  const float* Wk   = (const float*)d_in[4];
  const float* bk   = (const float*)d_in[5];
  const float* Wv   = (const float*)d_in[6];
  const float* bv   = (const float*)d_in[7];
  const float* Wo   = (const float*)d_in[8];
  const float* bo   = (const float*)d_in[9];
  const float* ln1g = (const float*)d_in[10];
  const float* ln1b = (const float*)d_in[11];
  const float* W1   = (const float*)d_in[12];
  const float* b1   = (const float*)d_in[13];
  const float* W2   = (const float*)d_in[14];
  const float* b2   = (const float*)d_in[15];
  const float* ln2g = (const float*)d_in[16];
  const float* ln2b = (const float*)d_in[17];
  float* out = (float*)d_out;
  char* ws = (char*)d_ws;

  u16*   wqkvT = (u16*)(ws + 0);              // [3072][1024] bf16
  u16*   woT   = (u16*)(ws + 6291456);        // [1024][1024]
  u16*   w1T   = (u16*)(ws + 8388608);        // [4096][1024]
  u16*   w2T   = (u16*)(ws + 16777216);       // [1024][4096]
  float* bqkv  = (float*)(ws + 25165824);     // [3072]
  float* cosT  = (float*)(ws + 25178112);     // [2048][32]
  float* sinT  = (float*)(ws + 25440256);
  float* x2    = (float*)(ws + 25702400);     // [4096][1024] f32
  u16*   lnbuf = (u16*)(ws + 42479616);       // [4096][1024] bf16 (ln1/ln2)
  u16*   vtb   = lnbuf;                       // vt[32][64][2048] overlays lnbuf
  u16*   qkv   = (u16*)(ws + 50868224);       // [4096][3072] bf16
  u16*   attnO = (u16*)(ws + 76034048);       // [4096][1024] bf16
  u16*   hbuf  = qkv;                         // [4096][4096] bf16 overlays qkv+attnO

  const dim3 blk(256);
  // weights -> B^T bf16
  transpose_conv<<<dim3(16, 16), blk, 0, stream>>>(Wq, wqkvT, 1024, 1024);
  transpose_conv<<<dim3(16, 16), blk, 0, stream>>>(Wk, wqkvT + 1024 * 1024, 1024, 1024);
  transpose_conv<<<dim3(16, 16), blk, 0, stream>>>(Wv, wqkvT + 2048 * 1024, 1024, 1024);
  transpose_conv<<<dim3(16, 16), blk, 0, stream>>>(Wo, woT, 1024, 1024);
  transpose_conv<<<dim3(64, 16), blk, 0, stream>>>(W1, w1T, 1024, 4096);
  transpose_conv<<<dim3(16, 64), blk, 0, stream>>>(W2, w2T, 4096, 1024);
  concat_bias<<<12, blk, 0, stream>>>(bq, bk, bv, bqkv);
  rope_tables<<<256, blk, 0, stream>>>(cosT, sinT);

  // LN1 -> fused QKV GEMM -> RoPE -> V^T -> attention
  ln_kernel<<<NR_, blk, 0, stream>>>(x, ln1g, ln1b, lnbuf);
  gemm_bt<0><<<768, blk, 0, stream>>>(lnbuf, wqkvT, bqkv, nullptr,
                                      qkv, NR_, 3072, 1024, 24);
  rope_apply<<<2048, blk, 0, stream>>>(qkv, cosT, sinT);
  v_transpose<<<dim3(64, 32), blk, 0, stream>>>(qkv, vtb);
  attn_kernel<<<1024, blk, 0, stream>>>(qkv, vtb, attnO);

  // O-proj + residual (f32) -> LN2 -> MLP
  gemm_bt<2><<<256, blk, 0, stream>>>(attnO, woT, bo, x, x2,
                                      NR_, 1024, 1024, 8);
  ln_kernel<<<NR_, blk, 0, stream>>>(x2, ln2g, ln2b, lnbuf);
  gemm_bt<1><<<1024, blk, 0, stream>>>(lnbuf, w1T, b1, nullptr,
                                       hbuf, NR_, 4096, 1024, 32);
  gemm_bt<2><<<256, blk, 0, stream>>>(hbuf, w2T, b2, x2, out,
                                      NR_, 1024, 4096, 8);
}